// Round 12
// baseline (65.728 us; speedup 1.0000x reference)
//
#include <hip/hip_runtime.h>
#include <hip/hip_bf16.h>
#include <cstdint>
#include <cstddef>

#define B_ 8
#define C_ 64
#define CI 32
#define N_ 4096
#define LOG2E 1.44269504088896340736f

typedef __attribute__((ext_vector_type(8))) short bf16x8;
typedef __attribute__((ext_vector_type(4))) float f32x4;
typedef __attribute__((ext_vector_type(16))) float f32x16;

static __device__ __forceinline__ ushort f2bf(float x) {
  union { float f; uint32_t u; } v; v.f = x;
  uint32_t r = v.u + 0x7FFFu + ((v.u >> 16) & 1u);
  return (ushort)(r >> 16);
}

static __device__ __forceinline__ uint32_t cvt_pk_bf16(float lo, float hi) {
  uint32_t r;
  asm("v_cvt_pk_bf16_f32 %0, %1, %2" : "=v"(r) : "v"(lo), "v"(hi));
  return r;
}

// -------- Kernel 1: 1x1-conv projections, W staged in LDS (r9-proven) ------
__global__ __launch_bounds__(256) void proj_kernel(
    const float* __restrict__ x,
    const float* __restrict__ Wg, const float* __restrict__ bg,
    const float* __restrict__ Wt, const float* __restrict__ bt,
    const float* __restrict__ Wp, const float* __restrict__ bp,
    ushort* __restrict__ theta_t, ushort* __restrict__ phi_t,
    ushort* __restrict__ gmat)
{
  __shared__ float WLt[C_ * CI];   // W transposed: [c][d], 8KB
  __shared__ float bL[CI];

  const int z = blockIdx.z;
  const float* W; const float* bias;
  if (z == 0)      { W = Wt; bias = bt; }
  else if (z == 1) { W = Wp; bias = bp; }
  else             { W = Wg; bias = bg; }

  const int t = threadIdx.x;
  #pragma unroll
  for (int k = 0; k < 8; ++k) {
    const int i = t + k * 256;            // i = d*C + c
    WLt[(i % C_) * CI + (i / C_)] = W[i];
  }
  if (t < CI) bL[t] = bias[t];
  __syncthreads();

  const int b = blockIdx.y;
  const int n = blockIdx.x * 64 + (t & 63);
  const int dq = t >> 6;                  // wave-uniform channel quarter
  const float* xb = x + ((size_t)b * C_) * N_ + n;

  float acc[8];
  #pragma unroll
  for (int i = 0; i < 8; ++i) acc[i] = bL[dq * 8 + i];

  #pragma unroll 8
  for (int c = 0; c < C_; ++c) {
    const float xv = xb[(size_t)c * N_];
    const float4 w0 = *(const float4*)&WLt[c * CI + dq * 8];
    const float4 w1 = *(const float4*)&WLt[c * CI + dq * 8 + 4];
    acc[0] = fmaf(w0.x, xv, acc[0]);
    acc[1] = fmaf(w0.y, xv, acc[1]);
    acc[2] = fmaf(w0.z, xv, acc[2]);
    acc[3] = fmaf(w0.w, xv, acc[3]);
    acc[4] = fmaf(w1.x, xv, acc[4]);
    acc[5] = fmaf(w1.y, xv, acc[5]);
    acc[6] = fmaf(w1.z, xv, acc[6]);
    acc[7] = fmaf(w1.w, xv, acc[7]);
  }

  if (z == 2) {
    #pragma unroll
    for (int i = 0; i < 8; ++i)
      gmat[((size_t)(b * CI) + dq * 8 + i) * N_ + n] = f2bf(acc[i]);
  } else {
    const float scale = (z == 0) ? LOG2E : 1.0f;
    uint32_t w[4];
    #pragma unroll
    for (int k = 0; k < 4; ++k)
      w[k] = (uint32_t)f2bf(acc[2 * k] * scale) |
             ((uint32_t)f2bf(acc[2 * k + 1] * scale) << 16);
    ushort* base = (z == 0) ? theta_t : phi_t;
    *(uint4*)(base + ((size_t)(b * N_) + n) * CI + dq * 8) =
        make_uint4(w[0], w[1], w[2], w[3]);
  }
}

// -------- Kernel 2: flash attention, 32x32 MFMA, in-register P -------------
// 8 waves = 8 m-eighths, q=64/wave (2 q-tiles of 32). QK 32x32x16 (2 chained
// d-halves) -> exp2 -> cvt_pk -> half-wave shfl_xor(32) exchange -> PV
// 32x32x16. No P LDS, no drains, no sched_barriers: pure dataflow.
__global__ __launch_bounds__(512, 2) void attn_kernel(
    const ushort* __restrict__ theta_t,
    const ushort* __restrict__ phi_t,
    const ushort* __restrict__ gmat,
    const float* __restrict__ Ww, const float* __restrict__ bw,
    const float* __restrict__ x, float* __restrict__ out)
{
  __shared__ float accS[4][32][64];   // merge acc slots, 32KB
  __shared__ float mlS[4][4][64];     // merge m/l slots (m0,m1,l0,l1)
  __shared__ float WwL[C_ * CI];      // 8KB
  __shared__ float Yl[32 * 66];       // 8.4KB

  const int tid = threadIdx.x;
  const int lane = tid & 63;
  const int mh = tid >> 6;            // wave = m-eighth 0..7
  const int bid = blockIdx.x;
  const int b = bid & 7;              // batch -> XCD slot (K/V L2-resident)
  const int n0 = (bid >> 3) * 64;
  const int q32 = lane & 31;
  const int h = lane >> 5;            // half-wave index

  #pragma unroll
  for (int i = 0; i < 4; ++i) WwL[tid + i * 512] = Ww[tid + i * 512];

  // Q B-frags (32x32x16): col=q32, k = dh*16 + h*8 + j
  bf16x8 qf[2][2];
  #pragma unroll
  for (int qt = 0; qt < 2; ++qt)
    #pragma unroll
    for (int dh = 0; dh < 2; ++dh)
      qf[qt][dh] = *(const bf16x8*)(theta_t +
          ((size_t)(b * N_ + n0 + qt * 32 + q32)) * CI + dh * 16 + h * 8);

  f32x16 acc[2];
  #pragma unroll
  for (int qt = 0; qt < 2; ++qt)
    #pragma unroll
    for (int r = 0; r < 16; ++r) acc[qt][r] = 0.f;
  float m_run[2] = {0.f, 0.f};
  float l_lane[2] = {0.f, 0.f};

  // K A-frag: row m = mq0 + toff + q32, k = dh*16 + h*8 + j
  const ushort* kf_base = phi_t + ((size_t)(b * N_ + mh * 512 + q32)) * CI + h * 8;
  // V A-frag: row d = q32, k(m) = toff + ks*16 + h*8 + j
  const ushort* vf_base = gmat + ((size_t)(b * CI + q32)) * N_ + mh * 512 + h * 8;

  const int NT = 8;                   // 512 rows / 64 per t-iter
  for (int t = 0; t < NT; ++t) {
    bf16x8 vf[4];
    #pragma unroll
    for (int ks = 0; ks < 4; ++ks)
      vf[ks] = *(const bf16x8*)(vf_base + t * 64 + ks * 16);

    #pragma unroll
    for (int msub = 0; msub < 2; ++msub) {
      const bf16x8 kfA = *(const bf16x8*)(kf_base +
          (size_t)(t * 64 + msub * 32) * CI);
      const bf16x8 kfB = *(const bf16x8*)(kf_base +
          (size_t)(t * 64 + msub * 32) * CI + 16);

      #pragma unroll
      for (int qt = 0; qt < 2; ++qt) {
        f32x16 z;
        #pragma unroll
        for (int r = 0; r < 16; ++r) z[r] = 0.f;
        __builtin_amdgcn_s_setprio(1);
        f32x16 f = __builtin_amdgcn_mfma_f32_32x32x16_bf16(
            kfA, qf[qt][0], z, 0, 0, 0);
        f = __builtin_amdgcn_mfma_f32_32x32x16_bf16(
            kfB, qf[qt][1], f, 0, 0, 0);
        __builtin_amdgcn_s_setprio(0);

        // softmax: p = exp2(f - m); m==0 fast path (wave-uniform branch)
        float p[16];
        if (m_run[qt] == 0.f) {
          #pragma unroll
          for (int r = 0; r < 16; ++r)
            p[r] = __builtin_amdgcn_exp2f(f[r]);
        } else {
          #pragma unroll
          for (int r = 0; r < 16; ++r)
            p[r] = __builtin_amdgcn_exp2f(f[r] - m_run[qt]);
        }
        float ls = 0.f;
        #pragma unroll
        for (int r = 0; r < 16; r += 4)
          ls += (p[r] + p[r + 1]) + (p[r + 2] + p[r + 3]);
        l_lane[qt] += ls;

        uint32_t w[8];
        #pragma unroll
        for (int j = 0; j < 8; ++j)
          w[j] = cvt_pk_bf16(p[2 * j], p[2 * j + 1]);

        // half-wave exchange: lane <-> lane^32
        // lo rows per reg-pair: {m0-3}=w0w1 {m8-11}=w2w3 {m16-19}=w4w5 {m24-27}=w6w7
        // hi rows: +4. PV B-frag k ascending needs:
        //   B0 (m 0..15):  lo=[w0,w1,hi.w0,hi.w1], hi=[lo.w2,lo.w3,w2,w3]
        //   B1 (m 16..31): lo=[w4,w5,hi.w4,hi.w5], hi=[lo.w6,lo.w7,w6,w7]
        const uint32_t s0 = h ? w[0] : w[2];
        const uint32_t s1 = h ? w[1] : w[3];
        const uint32_t s2 = h ? w[4] : w[6];
        const uint32_t s3 = h ? w[5] : w[7];
        const uint32_t r0 = (uint32_t)__shfl_xor((int)s0, 32, 64);
        const uint32_t r1 = (uint32_t)__shfl_xor((int)s1, 32, 64);
        const uint32_t r2 = (uint32_t)__shfl_xor((int)s2, 32, 64);
        const uint32_t r3 = (uint32_t)__shfl_xor((int)s3, 32, 64);

        union { uint32_t u[4]; bf16x8 v; } B0, B1;
        B0.u[0] = h ? r0 : w[0];
        B0.u[1] = h ? r1 : w[1];
        B0.u[2] = h ? w[2] : r0;
        B0.u[3] = h ? w[3] : r1;
        B1.u[0] = h ? r2 : w[4];
        B1.u[1] = h ? r3 : w[5];
        B1.u[2] = h ? w[6] : r2;
        B1.u[3] = h ? w[7] : r3;

        __builtin_amdgcn_s_setprio(1);
        acc[qt] = __builtin_amdgcn_mfma_f32_32x32x16_bf16(
            vf[msub * 2], B0.v, acc[qt], 0, 0, 0);
        acc[qt] = __builtin_amdgcn_mfma_f32_32x32x16_bf16(
            vf[msub * 2 + 1], B1.v, acc[qt], 0, 0, 0);
        __builtin_amdgcn_s_setprio(0);
      }
    }

    // l-threshold rescale: rare, exact power of 2 (l <= 2^53 between checks)
    #pragma unroll
    for (int qt = 0; qt < 2; ++qt) {
      if (__any(l_lane[qt] > 0x1p40f)) {
        #pragma unroll
        for (int r = 0; r < 16; ++r) acc[qt][r] *= 0x1p-64f;
        l_lane[qt] *= 0x1p-64f;
        m_run[qt] += 64.f;
      }
    }
  }

  // total l per q-column: both half-waves cover same q with disjoint m
  #pragma unroll
  for (int qt = 0; qt < 2; ++qt)
    l_lane[qt] += __shfl_xor(l_lane[qt], 32, 64);

  // ---- split-m merge: max-aware flash combine, 3-round tree ----
  #pragma unroll
  for (int r = 4; r >= 1; r >>= 1) {
    __syncthreads();
    if (mh >= r && mh < 2 * r) {
      const int slot = mh - r;
      #pragma unroll
      for (int qt = 0; qt < 2; ++qt)
        #pragma unroll
        for (int rr = 0; rr < 16; ++rr)
          accS[slot][qt * 16 + rr][lane] = acc[qt][rr];
      mlS[slot][0][lane] = m_run[0];
      mlS[slot][1][lane] = m_run[1];
      mlS[slot][2][lane] = l_lane[0];
      mlS[slot][3][lane] = l_lane[1];
    }
    __syncthreads();
    if (mh < r) {
      #pragma unroll
      for (int qt = 0; qt < 2; ++qt) {
        const float mb = mlS[mh][qt][lane];
        const float lb = mlS[mh][2 + qt][lane];
        const float mM = fmaxf(m_run[qt], mb);
        const float ea = __builtin_amdgcn_exp2f(m_run[qt] - mM);
        const float eb = __builtin_amdgcn_exp2f(mb - mM);
        #pragma unroll
        for (int rr = 0; rr < 16; ++rr)
          acc[qt][rr] = acc[qt][rr] * ea + accS[mh][qt * 16 + rr][lane] * eb;
        l_lane[qt] = l_lane[qt] * ea + lb * eb;
        m_run[qt] = mM;
      }
    }
  }
  __syncthreads();

  if (mh == 0) {
    #pragma unroll
    for (int qt = 0; qt < 2; ++qt) {
      const float inv = 1.0f / l_lane[qt];
      const int q = qt * 32 + q32;
      #pragma unroll
      for (int rr = 0; rr < 16; ++rr) {
        const int d = (rr & 3) + 8 * (rr >> 2) + 4 * h;
        Yl[d * 66 + q] = acc[qt][rr] * inv;
      }
    }
  }
  __syncthreads();

  // ---- fused out-projection + residual: out = Ww @ y + bw + x ----
  const int nl = tid & 63;
  const int cg = tid >> 6;
  float oacc[8];
  #pragma unroll
  for (int i = 0; i < 8; ++i) oacc[i] = bw[cg * 8 + i];
  #pragma unroll
  for (int d = 0; d < CI; ++d) {
    const float yv = Yl[d * 66 + nl];
    #pragma unroll
    for (int i = 0; i < 8; ++i)
      oacc[i] = fmaf(WwL[(cg * 8 + i) * CI + d], yv, oacc[i]);
  }
  #pragma unroll
  for (int i = 0; i < 8; ++i) {
    const size_t idx = ((size_t)(b * C_ + cg * 8 + i)) * N_ + n0 + nl;
    out[idx] = oacc[i] + x[idx];
  }
}

extern "C" void kernel_launch(void* const* d_in, const int* in_sizes, int n_in,
                              void* d_out, int out_size, void* d_ws, size_t ws_size,
                              hipStream_t stream) {
  const float* x  = (const float*)d_in[0];
  const float* Wg = (const float*)d_in[1];
  const float* bg = (const float*)d_in[2];
  const float* Wt = (const float*)d_in[3];
  const float* bt = (const float*)d_in[4];
  const float* Wp = (const float*)d_in[5];
  const float* bp = (const float*)d_in[6];
  const float* Ww = (const float*)d_in[7];
  const float* bw = (const float*)d_in[8];
  float* out = (float*)d_out;

  char* ws = (char*)d_ws;
  ushort* theta_t = (ushort*)(ws);
  ushort* phi_t   = (ushort*)(ws + (size_t)2 * 1024 * 1024);
  ushort* gmat    = (ushort*)(ws + (size_t)4 * 1024 * 1024);

  proj_kernel<<<dim3(N_ / 64, B_, 3), 256, 0, stream>>>(
      x, Wg, bg, Wt, bt, Wp, bp, theta_t, phi_t, gmat);
  attn_kernel<<<dim3((N_ / 64) * B_), 512, 0, stream>>>(
      theta_t, phi_t, gmat, Ww, bw, x, out);
}

// Round 13
// 61.505 us; speedup vs baseline: 1.0687x; 1.0687x over previous
//
#include <hip/hip_runtime.h>
#include <hip/hip_bf16.h>
#include <cstdint>
#include <cstddef>

#define B_ 8
#define C_ 64
#define CI 32
#define N_ 4096
#define LOG2E 1.44269504088896340736f

typedef __attribute__((ext_vector_type(8))) short bf16x8;
typedef __attribute__((ext_vector_type(4))) float f32x4;

static __device__ __forceinline__ ushort f2bf(float x) {
  union { float f; uint32_t u; } v; v.f = x;
  uint32_t r = v.u + 0x7FFFu + ((v.u >> 16) & 1u);
  return (ushort)(r >> 16);
}

static __device__ __forceinline__ uint32_t cvt_pk_bf16(float lo, float hi) {
  uint32_t r;
  asm("v_cvt_pk_bf16_f32 %0, %1, %2" : "=v"(r) : "v"(lo), "v"(hi));
  return r;
}

// -------- Kernel 1: FUSED 1x1-conv projections (x read once) ---------------
// theta_t (B,N,CI) bf16 scaled by log2e; phi_t (B,N,CI); gmat (B,CI,N).
// 512 thr: lane n (64) x dg (8 groups of 4 channels). W transposed in LDS.
__global__ __launch_bounds__(512) void proj_kernel(
    const float* __restrict__ x,
    const float* __restrict__ Wg, const float* __restrict__ bg,
    const float* __restrict__ Wt, const float* __restrict__ bt,
    const float* __restrict__ Wp, const float* __restrict__ bp,
    ushort* __restrict__ theta_t, ushort* __restrict__ phi_t,
    ushort* __restrict__ gmat)
{
  __shared__ float WT[C_ * CI], WP[C_ * CI], WG[C_ * CI];  // [c][d], 24KB
  __shared__ float bT[CI], bP[CI], bG[CI];

  const int t = threadIdx.x;
  #pragma unroll
  for (int k = 0; k < 4; ++k) {
    const int i = t + k * 512;            // i = d*C + c
    const int j = (i & 63) * CI + (i >> 6);
    WT[j] = Wt[i]; WP[j] = Wp[i]; WG[j] = Wg[i];
  }
  if (t < CI) { bT[t] = bt[t]; bP[t] = bp[t]; bG[t] = bg[t]; }
  __syncthreads();

  const int b = blockIdx.y;
  const int n = blockIdx.x * 64 + (t & 63);
  const int dg = t >> 6;                  // wave-uniform: 8 groups of 4 ch
  const float* xb = x + ((size_t)b * C_) * N_ + n;

  float at[4], ap[4], ag[4];
  #pragma unroll
  for (int i = 0; i < 4; ++i) {
    at[i] = bT[dg * 4 + i]; ap[i] = bP[dg * 4 + i]; ag[i] = bG[dg * 4 + i];
  }

  #pragma unroll 8
  for (int c = 0; c < C_; ++c) {
    const float xv = xb[(size_t)c * N_];
    const float4 wt4 = *(const float4*)&WT[c * CI + dg * 4];
    const float4 wp4 = *(const float4*)&WP[c * CI + dg * 4];
    const float4 wg4 = *(const float4*)&WG[c * CI + dg * 4];
    at[0] = fmaf(wt4.x, xv, at[0]); at[1] = fmaf(wt4.y, xv, at[1]);
    at[2] = fmaf(wt4.z, xv, at[2]); at[3] = fmaf(wt4.w, xv, at[3]);
    ap[0] = fmaf(wp4.x, xv, ap[0]); ap[1] = fmaf(wp4.y, xv, ap[1]);
    ap[2] = fmaf(wp4.z, xv, ap[2]); ap[3] = fmaf(wp4.w, xv, ap[3]);
    ag[0] = fmaf(wg4.x, xv, ag[0]); ag[1] = fmaf(wg4.y, xv, ag[1]);
    ag[2] = fmaf(wg4.z, xv, ag[2]); ag[3] = fmaf(wg4.w, xv, ag[3]);
  }

  uint2 wt2, wp2;
  wt2.x = (uint32_t)f2bf(at[0] * LOG2E) | ((uint32_t)f2bf(at[1] * LOG2E) << 16);
  wt2.y = (uint32_t)f2bf(at[2] * LOG2E) | ((uint32_t)f2bf(at[3] * LOG2E) << 16);
  wp2.x = (uint32_t)f2bf(ap[0]) | ((uint32_t)f2bf(ap[1]) << 16);
  wp2.y = (uint32_t)f2bf(ap[2]) | ((uint32_t)f2bf(ap[3]) << 16);
  *(uint2*)(theta_t + ((size_t)(b * N_) + n) * CI + dg * 4) = wt2;
  *(uint2*)(phi_t   + ((size_t)(b * N_) + n) * CI + dg * 4) = wp2;
  #pragma unroll
  for (int i = 0; i < 4; ++i)
    gmat[((size_t)(b * CI) + dg * 4 + i) * N_ + n] = f2bf(ag[i]);
}

// -------- Kernel 2: flash attention (r11 core; no setprio; vf prefetch) ----
__global__ __launch_bounds__(512, 2) void attn_kernel(
    const ushort* __restrict__ theta_t,
    const ushort* __restrict__ phi_t,
    const ushort* __restrict__ gmat,
    const float* __restrict__ Ww, const float* __restrict__ bw,
    const float* __restrict__ x, float* __restrict__ out)
{
  __shared__ union {
    ushort pt[8][2][16 * 64];     // per-wave ping-pong P tiles (main loop)
    float  accS[4][32][64];       // merge acc slots (merge phase)
  } Sh;
  __shared__ float mlS[4][8][64]; // merge m/l slots
  __shared__ float WwL[C_ * CI];
  __shared__ float Yl[32 * 66];

  const int tid = threadIdx.x;
  const int lane = tid & 63;
  const int mh = tid >> 6;        // wave = m-eighth 0..7
  const int bid = blockIdx.x;
  const int b = bid & 7;          // batch -> XCD slot (K/V L2-resident)
  const int n0 = (bid >> 3) * 64;
  const int g4 = lane >> 4;
  const int c16 = lane & 15;
  const int sw = (c16 & 7) << 4;

  #pragma unroll
  for (int i = 0; i < 4; ++i) WwL[tid + i * 512] = Ww[tid + i * 512];

  bf16x8 qfrag[4];
  #pragma unroll
  for (int s = 0; s < 4; ++s)
    qfrag[s] = *(const bf16x8*)(theta_t +
        ((size_t)(b * N_ + n0 + s * 16 + c16)) * CI + g4 * 8);

  f32x4 acc[4][2];
  f32x4 cinit[4];                 // = splat(-m_run[s]); lives in regs
  #pragma unroll
  for (int s = 0; s < 4; ++s) {
    acc[s][0] = (f32x4){0.f, 0.f, 0.f, 0.f};
    acc[s][1] = (f32x4){0.f, 0.f, 0.f, 0.f};
    cinit[s]  = (f32x4){0.f, 0.f, 0.f, 0.f};
  }
  float l_lane[4] = {0.f, 0.f, 0.f, 0.f};

  const int mq0 = mh * 512;
  const ushort* kbase = phi_t + ((size_t)(b * N_ + mq0 + c16)) * CI + g4 * 8;
  const ushort* vb0 = gmat + ((size_t)(b * CI + c16)) * N_ + mq0 + g4 * 8;
  const ushort* vb1 = vb0 + (size_t)16 * N_;

  char* pw[2][4]; const char* prd[2][2];
  #pragma unroll
  for (int pb = 0; pb < 2; ++pb) {
    #pragma unroll
    for (int mt = 0; mt < 4; ++mt)
      pw[pb][mt] = (char*)Sh.pt[mh][pb] + ((c16 * 128 + mt * 32 + g4 * 8) ^ sw);
    #pragma unroll
    for (int ks = 0; ks < 2; ++ks)
      prd[pb][ks] = (const char*)Sh.pt[mh][pb] +
                    ((c16 * 128 + ks * 64 + g4 * 16) ^ sw);
  }

  bf16x8 kf[4], kfn[4], vf0[2], vf1[2], vfn0[2], vfn1[2];
  #pragma unroll
  for (int mt = 0; mt < 4; ++mt)
    kfn[mt] = *(const bf16x8*)(kbase + (size_t)(mt * 16) * CI);
  #pragma unroll
  for (int ks = 0; ks < 2; ++ks) {
    vfn0[ks] = *(const bf16x8*)(vb0 + ks * 32);
    vfn1[ks] = *(const bf16x8*)(vb1 + ks * 32);
  }

  const int NT = 8;               // 512 rows / 64 per tile
  for (int t = 0; t < NT; ++t) {
    #pragma unroll
    for (int mt = 0; mt < 4; ++mt) kf[mt] = kfn[mt];
    #pragma unroll
    for (int ks = 0; ks < 2; ++ks) {
      vf0[ks] = vfn0[ks]; vf1[ks] = vfn1[ks];
    }
    const int tn = (t + 1 < NT) ? t + 1 : t;
    #pragma unroll
    for (int mt = 0; mt < 4; ++mt)
      kfn[mt] = *(const bf16x8*)(kbase + (size_t)(tn * 64 + mt * 16) * CI);
    #pragma unroll
    for (int ks = 0; ks < 2; ++ks) {
      vfn0[ks] = *(const bf16x8*)(vb0 + tn * 64 + ks * 32);
      vfn1[ks] = *(const bf16x8*)(vb1 + tn * 64 + ks * 32);
    }

    #pragma unroll
    for (int s = 0; s < 4; ++s) {
      const int pb = s & 1;
      f32x4 f[4];
      #pragma unroll
      for (int mt = 0; mt < 4; ++mt)
        f[mt] = __builtin_amdgcn_mfma_f32_16x16x32_bf16(
            kf[mt], qfrag[s], cinit[s], 0, 0, 0);   // f = K.Q - m (free sub)

      // p = exp2(f); l accumulates; no fmax tree (l-threshold guards range)
      float pv[4][4];
      #pragma unroll
      for (int mt = 0; mt < 4; ++mt) {
        #pragma unroll
        for (int rr = 0; rr < 4; ++rr)
          pv[mt][rr] = __builtin_amdgcn_exp2f(f[mt][rr]);
        l_lane[s] += (pv[mt][0] + pv[mt][1]) + (pv[mt][2] + pv[mt][3]);
      }
      #pragma unroll
      for (int mt = 0; mt < 4; ++mt) {
        uint2 wv;
        wv.x = cvt_pk_bf16(pv[mt][0], pv[mt][1]);
        wv.y = cvt_pk_bf16(pv[mt][2], pv[mt][3]);
        *(uint2*)pw[pb][mt] = wv;
      }
      // pin write->read order (compiler can't relate XOR'd char* aliases)
      asm volatile("s_waitcnt lgkmcnt(0)" ::: "memory");
      __builtin_amdgcn_sched_barrier(0);

      #pragma unroll
      for (int ks = 0; ks < 2; ++ks) {
        const bf16x8 pfrag = *(const bf16x8*)prd[pb][ks];
        acc[s][0] = __builtin_amdgcn_mfma_f32_16x16x32_bf16(
            vf0[ks], pfrag, acc[s][0], 0, 0, 0);
        acc[s][1] = __builtin_amdgcn_mfma_f32_16x16x32_bf16(
            vf1[ks], pfrag, acc[s][1], 0, 0, 0);
      }

      // l-threshold rescale: rare, exact power of 2; keeps l,p,acc in range.
      if (__any(l_lane[s] > 0x1p40f)) {
        const float sc = 0x1p-64f;
        acc[s][0] *= sc; acc[s][1] *= sc; l_lane[s] *= sc;
        #pragma unroll
        for (int rr = 0; rr < 4; ++rr) cinit[s][rr] -= 64.f;
      }
    }
  }

  // total l per q-column: sum the 4 g4 partials
  float m_run[4];
  #pragma unroll
  for (int s = 0; s < 4; ++s) {
    l_lane[s] += __shfl_xor(l_lane[s], 16);
    l_lane[s] += __shfl_xor(l_lane[s], 32);
    m_run[s] = -cinit[s][0];
  }

  // ---- split-m merge: max-aware flash combine, 3-round tree (r7-proven) ----
  #pragma unroll
  for (int r = 4; r >= 1; r >>= 1) {
    __syncthreads();
    if (mh >= r && mh < 2 * r) {
      float* ad = &Sh.accS[mh - r][0][0] + lane;
      float* md = &mlS[mh - r][0][0] + lane;
      #pragma unroll
      for (int s = 0; s < 4; ++s) {
        #pragma unroll
        for (int rr = 0; rr < 4; ++rr) {
          ad[(s * 8 + rr) * 64]     = acc[s][0][rr];
          ad[(s * 8 + 4 + rr) * 64] = acc[s][1][rr];
        }
        md[s * 64]       = m_run[s];
        md[(4 + s) * 64] = l_lane[s];
      }
    }
    __syncthreads();
    if (mh < r) {
      const float* as_ = &Sh.accS[mh][0][0] + lane;
      const float* ms_ = &mlS[mh][0][0] + lane;
      #pragma unroll
      for (int s = 0; s < 4; ++s) {
        const float mb = ms_[s * 64];
        const float lb = ms_[(4 + s) * 64];
        const float mM = fmaxf(m_run[s], mb);
        const float ea = __builtin_amdgcn_exp2f(m_run[s] - mM);
        const float eb = __builtin_amdgcn_exp2f(mb - mM);
        #pragma unroll
        for (int rr = 0; rr < 4; ++rr) {
          acc[s][0][rr] = acc[s][0][rr] * ea + as_[(s * 8 + rr) * 64] * eb;
          acc[s][1][rr] = acc[s][1][rr] * ea + as_[(s * 8 + 4 + rr) * 64] * eb;
        }
        l_lane[s] = l_lane[s] * ea + lb * eb;
        m_run[s] = mM;
      }
    }
  }
  __syncthreads();

  if (mh == 0) {
    #pragma unroll
    for (int s = 0; s < 4; ++s) {
      const float inv = 1.0f / l_lane[s];
      const int q = s * 16 + c16;
      #pragma unroll
      for (int rr = 0; rr < 4; ++rr) {
        Yl[(g4 * 4 + rr) * 66 + q]      = acc[s][0][rr] * inv;
        Yl[(16 + g4 * 4 + rr) * 66 + q] = acc[s][1][rr] * inv;
      }
    }
  }
  __syncthreads();

  // ---- fused out-projection + residual: out = Ww @ y + bw + x ----
  const int nl = tid & 63;
  const int cg = tid >> 6;
  float oacc[8];
  #pragma unroll
  for (int i = 0; i < 8; ++i) oacc[i] = bw[cg * 8 + i];
  #pragma unroll
  for (int d = 0; d < CI; ++d) {
    const float yv = Yl[d * 66 + nl];
    #pragma unroll
    for (int i = 0; i < 8; ++i)
      oacc[i] = fmaf(WwL[(cg * 8 + i) * CI + d], yv, oacc[i]);
  }
  #pragma unroll
  for (int i = 0; i < 8; ++i) {
    const size_t idx = ((size_t)(b * C_ + cg * 8 + i)) * N_ + n0 + nl;
    out[idx] = oacc[i] + x[idx];
  }
}

extern "C" void kernel_launch(void* const* d_in, const int* in_sizes, int n_in,
                              void* d_out, int out_size, void* d_ws, size_t ws_size,
                              hipStream_t stream) {
  const float* x  = (const float*)d_in[0];
  const float* Wg = (const float*)d_in[1];
  const float* bg = (const float*)d_in[2];
  const float* Wt = (const float*)d_in[3];
  const float* bt = (const float*)d_in[4];
  const float* Wp = (const float*)d_in[5];
  const float* bp = (const float*)d_in[6];
  const float* Ww = (const float*)d_in[7];
  const float* bw = (const float*)d_in[8];
  float* out = (float*)d_out;

  char* ws = (char*)d_ws;
  ushort* theta_t = (ushort*)(ws);
  ushort* phi_t   = (ushort*)(ws + (size_t)2 * 1024 * 1024);
  ushort* gmat    = (ushort*)(ws + (size_t)4 * 1024 * 1024);

  proj_kernel<<<dim3(N_ / 64, B_), 512, 0, stream>>>(
      x, Wg, bg, Wt, bt, Wp, bp, theta_t, phi_t, gmat);
  attn_kernel<<<dim3((N_ / 64) * B_), 512, 0, stream>>>(
      theta_t, phi_t, gmat, Ww, bw, x, out);
}

// Round 14
// 60.171 us; speedup vs baseline: 1.0924x; 1.0222x over previous
//
#include <hip/hip_runtime.h>
#include <hip/hip_bf16.h>
#include <cstdint>
#include <cstddef>

#define B_ 8
#define C_ 64
#define CI 32
#define N_ 4096
#define LOG2E 1.44269504088896340736f

typedef __attribute__((ext_vector_type(8))) short bf16x8;
typedef __attribute__((ext_vector_type(4))) float f32x4;

static __device__ __forceinline__ ushort f2bf(float x) {
  union { float f; uint32_t u; } v; v.f = x;
  uint32_t r = v.u + 0x7FFFu + ((v.u >> 16) & 1u);
  return (ushort)(r >> 16);
}

static __device__ __forceinline__ uint32_t cvt_pk_bf16(float lo, float hi) {
  uint32_t r;
  asm("v_cvt_pk_bf16_f32 %0, %1, %2" : "=v"(r) : "v"(lo), "v"(hi));
  return r;
}

// -------- Kernel 1: fused 1x1-conv projections, scalar W loads -------------
// W accesses are wave-uniform (dg is per-wave): force uniformity via
// readfirstlane so they become s_load (SMEM/K$ pipe), not DS/VMEM.
// theta_t (B,N,CI) bf16 scaled by log2e; phi_t (B,N,CI); gmat (B,CI,N).
__global__ __launch_bounds__(512) void proj_kernel(
    const float* __restrict__ x,
    const float* __restrict__ Wg, const float* __restrict__ bg,
    const float* __restrict__ Wt, const float* __restrict__ bt,
    const float* __restrict__ Wp, const float* __restrict__ bp,
    ushort* __restrict__ theta_t, ushort* __restrict__ phi_t,
    ushort* __restrict__ gmat)
{
  const int t = threadIdx.x;
  const int b = blockIdx.y;
  const int n = blockIdx.x * 64 + (t & 63);
  const int dg = __builtin_amdgcn_readfirstlane(t >> 6);  // uniform 0..7
  const float* xb = x + ((size_t)b * C_) * N_ + n;
  const float* WtR = Wt + dg * 4 * C_;   // rows d = dg*4 .. dg*4+3 (uniform)
  const float* WpR = Wp + dg * 4 * C_;
  const float* WgR = Wg + dg * 4 * C_;

  float at[4], ap[4], ag[4];
  #pragma unroll
  for (int i = 0; i < 4; ++i) {
    at[i] = bt[dg * 4 + i]; ap[i] = bp[dg * 4 + i]; ag[i] = bg[dg * 4 + i];
  }

  #pragma unroll
  for (int c0 = 0; c0 < C_; c0 += 4) {
    float xv[4];
    #pragma unroll
    for (int j = 0; j < 4; ++j) xv[j] = xb[(size_t)(c0 + j) * N_];
    #pragma unroll
    for (int i = 0; i < 4; ++i) {
      const float4 wt4 = *(const float4*)&WtR[i * C_ + c0];  // s_load_dwordx4
      const float4 wp4 = *(const float4*)&WpR[i * C_ + c0];
      const float4 wg4 = *(const float4*)&WgR[i * C_ + c0];
      at[i] = fmaf(wt4.x, xv[0], at[i]); at[i] = fmaf(wt4.y, xv[1], at[i]);
      at[i] = fmaf(wt4.z, xv[2], at[i]); at[i] = fmaf(wt4.w, xv[3], at[i]);
      ap[i] = fmaf(wp4.x, xv[0], ap[i]); ap[i] = fmaf(wp4.y, xv[1], ap[i]);
      ap[i] = fmaf(wp4.z, xv[2], ap[i]); ap[i] = fmaf(wp4.w, xv[3], ap[i]);
      ag[i] = fmaf(wg4.x, xv[0], ag[i]); ag[i] = fmaf(wg4.y, xv[1], ag[i]);
      ag[i] = fmaf(wg4.z, xv[2], ag[i]); ag[i] = fmaf(wg4.w, xv[3], ag[i]);
    }
  }

  uint2 wt2, wp2;
  wt2.x = (uint32_t)f2bf(at[0] * LOG2E) | ((uint32_t)f2bf(at[1] * LOG2E) << 16);
  wt2.y = (uint32_t)f2bf(at[2] * LOG2E) | ((uint32_t)f2bf(at[3] * LOG2E) << 16);
  wp2.x = (uint32_t)f2bf(ap[0]) | ((uint32_t)f2bf(ap[1]) << 16);
  wp2.y = (uint32_t)f2bf(ap[2]) | ((uint32_t)f2bf(ap[3]) << 16);
  *(uint2*)(theta_t + ((size_t)(b * N_) + n) * CI + dg * 4) = wt2;
  *(uint2*)(phi_t   + ((size_t)(b * N_) + n) * CI + dg * 4) = wp2;
  #pragma unroll
  for (int i = 0; i < 4; ++i)
    gmat[((size_t)(b * CI) + dg * 4 + i) * N_ + n] = f2bf(ag[i]);
}

// -------- Kernel 2: flash attention (r13 core; Yl folded into LDS union) ---
// LDS 48.3KB -> 3 blocks/CU (24 waves, 6/SIMD) vs r13's 2.
__global__ __launch_bounds__(512, 2) void attn_kernel(
    const ushort* __restrict__ theta_t,
    const ushort* __restrict__ phi_t,
    const ushort* __restrict__ gmat,
    const float* __restrict__ Ww, const float* __restrict__ bw,
    const float* __restrict__ x, float* __restrict__ out)
{
  __shared__ union {
    ushort pt[8][2][16 * 64];     // per-wave ping-pong P tiles (main loop)
    float  accS[4][32][64];       // merge acc slots (merge phase)
    float  yl[32 * 66];           // y tile (after final merge sync)
  } Sh;
  __shared__ float mlS[4][8][64]; // merge m/l slots
  __shared__ float WwL[C_ * CI];

  const int tid = threadIdx.x;
  const int lane = tid & 63;
  const int mh = tid >> 6;        // wave = m-eighth 0..7
  const int bid = blockIdx.x;
  const int b = bid & 7;          // batch -> XCD slot (K/V L2-resident)
  const int n0 = (bid >> 3) * 64;
  const int g4 = lane >> 4;
  const int c16 = lane & 15;
  const int sw = (c16 & 7) << 4;

  #pragma unroll
  for (int i = 0; i < 4; ++i) WwL[tid + i * 512] = Ww[tid + i * 512];

  bf16x8 qfrag[4];
  #pragma unroll
  for (int s = 0; s < 4; ++s)
    qfrag[s] = *(const bf16x8*)(theta_t +
        ((size_t)(b * N_ + n0 + s * 16 + c16)) * CI + g4 * 8);

  f32x4 acc[4][2];
  f32x4 cinit[4];                 // = splat(-m_run[s]); lives in regs
  #pragma unroll
  for (int s = 0; s < 4; ++s) {
    acc[s][0] = (f32x4){0.f, 0.f, 0.f, 0.f};
    acc[s][1] = (f32x4){0.f, 0.f, 0.f, 0.f};
    cinit[s]  = (f32x4){0.f, 0.f, 0.f, 0.f};
  }
  float l_lane[4] = {0.f, 0.f, 0.f, 0.f};

  const int mq0 = mh * 512;
  const ushort* kbase = phi_t + ((size_t)(b * N_ + mq0 + c16)) * CI + g4 * 8;
  const ushort* vb0 = gmat + ((size_t)(b * CI + c16)) * N_ + mq0 + g4 * 8;
  const ushort* vb1 = vb0 + (size_t)16 * N_;

  char* pw[2][4]; const char* prd[2][2];
  #pragma unroll
  for (int pb = 0; pb < 2; ++pb) {
    #pragma unroll
    for (int mt = 0; mt < 4; ++mt)
      pw[pb][mt] = (char*)Sh.pt[mh][pb] + ((c16 * 128 + mt * 32 + g4 * 8) ^ sw);
    #pragma unroll
    for (int ks = 0; ks < 2; ++ks)
      prd[pb][ks] = (const char*)Sh.pt[mh][pb] +
                    ((c16 * 128 + ks * 64 + g4 * 16) ^ sw);
  }

  bf16x8 kf[4], kfn[4], vf0[2], vf1[2];
  #pragma unroll
  for (int mt = 0; mt < 4; ++mt)
    kfn[mt] = *(const bf16x8*)(kbase + (size_t)(mt * 16) * CI);

  const int NT = 8;               // 512 rows / 64 per tile
  for (int t = 0; t < NT; ++t) {
    #pragma unroll
    for (int mt = 0; mt < 4; ++mt) kf[mt] = kfn[mt];
    const int tn = (t + 1 < NT) ? t + 1 : t;
    #pragma unroll
    for (int mt = 0; mt < 4; ++mt)
      kfn[mt] = *(const bf16x8*)(kbase + (size_t)(tn * 64 + mt * 16) * CI);
    #pragma unroll
    for (int ks = 0; ks < 2; ++ks) {
      vf0[ks] = *(const bf16x8*)(vb0 + t * 64 + ks * 32);
      vf1[ks] = *(const bf16x8*)(vb1 + t * 64 + ks * 32);
    }

    #pragma unroll
    for (int s = 0; s < 4; ++s) {
      const int pb = s & 1;
      f32x4 f[4];
      #pragma unroll
      for (int mt = 0; mt < 4; ++mt)
        f[mt] = __builtin_amdgcn_mfma_f32_16x16x32_bf16(
            kf[mt], qfrag[s], cinit[s], 0, 0, 0);   // f = K.Q - m (free sub)

      // p = exp2(f); l accumulates; no fmax tree (l-threshold guards range)
      float pv[4][4];
      #pragma unroll
      for (int mt = 0; mt < 4; ++mt) {
        #pragma unroll
        for (int rr = 0; rr < 4; ++rr)
          pv[mt][rr] = __builtin_amdgcn_exp2f(f[mt][rr]);
        l_lane[s] += (pv[mt][0] + pv[mt][1]) + (pv[mt][2] + pv[mt][3]);
      }
      #pragma unroll
      for (int mt = 0; mt < 4; ++mt) {
        uint2 wv;
        wv.x = cvt_pk_bf16(pv[mt][0], pv[mt][1]);
        wv.y = cvt_pk_bf16(pv[mt][2], pv[mt][3]);
        *(uint2*)pw[pb][mt] = wv;
      }
      // pin write->read order (compiler can't relate XOR'd char* aliases)
      asm volatile("s_waitcnt lgkmcnt(0)" ::: "memory");
      __builtin_amdgcn_sched_barrier(0);

      #pragma unroll
      for (int ks = 0; ks < 2; ++ks) {
        const bf16x8 pfrag = *(const bf16x8*)prd[pb][ks];
        acc[s][0] = __builtin_amdgcn_mfma_f32_16x16x32_bf16(
            vf0[ks], pfrag, acc[s][0], 0, 0, 0);
        acc[s][1] = __builtin_amdgcn_mfma_f32_16x16x32_bf16(
            vf1[ks], pfrag, acc[s][1], 0, 0, 0);
      }

      // l-threshold rescale: rare, exact power of 2; keeps l,p,acc in range.
      if (__any(l_lane[s] > 0x1p40f)) {
        const float sc = 0x1p-64f;
        acc[s][0] *= sc; acc[s][1] *= sc; l_lane[s] *= sc;
        #pragma unroll
        for (int rr = 0; rr < 4; ++rr) cinit[s][rr] -= 64.f;
      }
    }
  }

  // total l per q-column: sum the 4 g4 partials
  float m_run[4];
  #pragma unroll
  for (int s = 0; s < 4; ++s) {
    l_lane[s] += __shfl_xor(l_lane[s], 16);
    l_lane[s] += __shfl_xor(l_lane[s], 32);
    m_run[s] = -cinit[s][0];
  }

  // ---- split-m merge: max-aware flash combine, 3-round tree (r7-proven) ----
  #pragma unroll
  for (int r = 4; r >= 1; r >>= 1) {
    __syncthreads();
    if (mh >= r && mh < 2 * r) {
      float* ad = &Sh.accS[mh - r][0][0] + lane;
      float* md = &mlS[mh - r][0][0] + lane;
      #pragma unroll
      for (int s = 0; s < 4; ++s) {
        #pragma unroll
        for (int rr = 0; rr < 4; ++rr) {
          ad[(s * 8 + rr) * 64]     = acc[s][0][rr];
          ad[(s * 8 + 4 + rr) * 64] = acc[s][1][rr];
        }
        md[s * 64]       = m_run[s];
        md[(4 + s) * 64] = l_lane[s];
      }
    }
    __syncthreads();
    if (mh < r) {
      const float* as_ = &Sh.accS[mh][0][0] + lane;
      const float* ms_ = &mlS[mh][0][0] + lane;
      #pragma unroll
      for (int s = 0; s < 4; ++s) {
        const float mb = ms_[s * 64];
        const float lb = ms_[(4 + s) * 64];
        const float mM = fmaxf(m_run[s], mb);
        const float ea = __builtin_amdgcn_exp2f(m_run[s] - mM);
        const float eb = __builtin_amdgcn_exp2f(mb - mM);
        #pragma unroll
        for (int rr = 0; rr < 4; ++rr) {
          acc[s][0][rr] = acc[s][0][rr] * ea + as_[(s * 8 + rr) * 64] * eb;
          acc[s][1][rr] = acc[s][1][rr] * ea + as_[(s * 8 + 4 + rr) * 64] * eb;
        }
        l_lane[s] = l_lane[s] * ea + lb * eb;
        m_run[s] = mM;
      }
    }
  }
  __syncthreads();                // all merge reads done; Sh reusable as Yl

  float* const Yl = Sh.yl;        // aliases dead pt/accS (barrier-ordered)
  if (mh == 0) {
    #pragma unroll
    for (int s = 0; s < 4; ++s) {
      const float inv = 1.0f / l_lane[s];
      const int q = s * 16 + c16;
      #pragma unroll
      for (int rr = 0; rr < 4; ++rr) {
        Yl[(g4 * 4 + rr) * 66 + q]      = acc[s][0][rr] * inv;
        Yl[(16 + g4 * 4 + rr) * 66 + q] = acc[s][1][rr] * inv;
      }
    }
  }
  __syncthreads();

  // ---- fused out-projection + residual: out = Ww @ y + bw + x ----
  const int nl = tid & 63;
  const int cg = tid >> 6;
  float oacc[8];
  #pragma unroll
  for (int i = 0; i < 8; ++i) oacc[i] = bw[cg * 8 + i];
  #pragma unroll
  for (int d = 0; d < CI; ++d) {
    const float yv = Yl[d * 66 + nl];
    #pragma unroll
    for (int i = 0; i < 8; ++i)
      oacc[i] = fmaf(WwL[(cg * 8 + i) * CI + d], yv, oacc[i]);
  }
  #pragma unroll
  for (int i = 0; i < 8; ++i) {
    const size_t idx = ((size_t)(b * C_ + cg * 8 + i)) * N_ + n0 + nl;
    out[idx] = oacc[i] + x[idx];
  }
}

extern "C" void kernel_launch(void* const* d_in, const int* in_sizes, int n_in,
                              void* d_out, int out_size, void* d_ws, size_t ws_size,
                              hipStream_t stream) {
  const float* x  = (const float*)d_in[0];
  const float* Wg = (const float*)d_in[1];
  const float* bg = (const float*)d_in[2];
  const float* Wt = (const float*)d_in[3];
  const float* bt = (const float*)d_in[4];
  const float* Wp = (const float*)d_in[5];
  const float* bp = (const float*)d_in[6];
  const float* Ww = (const float*)d_in[7];
  const float* bw = (const float*)d_in[8];
  float* out = (float*)d_out;

  char* ws = (char*)d_ws;
  ushort* theta_t = (ushort*)(ws);
  ushort* phi_t   = (ushort*)(ws + (size_t)2 * 1024 * 1024);
  ushort* gmat    = (ushort*)(ws + (size_t)4 * 1024 * 1024);

  proj_kernel<<<dim3(N_ / 64, B_), 512, 0, stream>>>(
      x, Wg, bg, Wt, bt, Wp, bp, theta_t, phi_t, gmat);
  attn_kernel<<<dim3((N_ / 64) * B_), 512, 0, stream>>>(
      theta_t, phi_t, gmat, Ww, bw, x, out);
}

// Round 15
// 60.072 us; speedup vs baseline: 1.0942x; 1.0016x over previous
//
#include <hip/hip_runtime.h>
#include <hip/hip_bf16.h>
#include <cstdint>
#include <cstddef>

#define B_ 8
#define C_ 64
#define CI 32
#define N_ 4096
#define LOG2E 1.44269504088896340736f

typedef __attribute__((ext_vector_type(8))) short bf16x8;
typedef __attribute__((ext_vector_type(4))) float f32x4;

static __device__ __forceinline__ ushort f2bf(float x) {
  union { float f; uint32_t u; } v; v.f = x;
  uint32_t r = v.u + 0x7FFFu + ((v.u >> 16) & 1u);
  return (ushort)(r >> 16);
}

static __device__ __forceinline__ uint32_t cvt_pk_bf16(float lo, float hi) {
  uint32_t r;
  asm("v_cvt_pk_bf16_f32 %0, %1, %2" : "=v"(r) : "v"(lo), "v"(hi));
  return r;
}

// -------- Kernel 1: fused 1x1-conv projections, scalar W loads (r14) -------
__global__ __launch_bounds__(512) void proj_kernel(
    const float* __restrict__ x,
    const float* __restrict__ Wg, const float* __restrict__ bg,
    const float* __restrict__ Wt, const float* __restrict__ bt,
    const float* __restrict__ Wp, const float* __restrict__ bp,
    ushort* __restrict__ theta_t, ushort* __restrict__ phi_t,
    ushort* __restrict__ gmat)
{
  const int t = threadIdx.x;
  const int b = blockIdx.y;
  const int n = blockIdx.x * 64 + (t & 63);
  const int dg = __builtin_amdgcn_readfirstlane(t >> 6);  // uniform 0..7
  const float* xb = x + ((size_t)b * C_) * N_ + n;
  const float* WtR = Wt + dg * 4 * C_;
  const float* WpR = Wp + dg * 4 * C_;
  const float* WgR = Wg + dg * 4 * C_;

  float at[4], ap[4], ag[4];
  #pragma unroll
  for (int i = 0; i < 4; ++i) {
    at[i] = bt[dg * 4 + i]; ap[i] = bp[dg * 4 + i]; ag[i] = bg[dg * 4 + i];
  }

  #pragma unroll
  for (int c0 = 0; c0 < C_; c0 += 4) {
    float xv[4];
    #pragma unroll
    for (int j = 0; j < 4; ++j) xv[j] = xb[(size_t)(c0 + j) * N_];
    #pragma unroll
    for (int i = 0; i < 4; ++i) {
      const float4 wt4 = *(const float4*)&WtR[i * C_ + c0];
      const float4 wp4 = *(const float4*)&WpR[i * C_ + c0];
      const float4 wg4 = *(const float4*)&WgR[i * C_ + c0];
      at[i] = fmaf(wt4.x, xv[0], at[i]); at[i] = fmaf(wt4.y, xv[1], at[i]);
      at[i] = fmaf(wt4.z, xv[2], at[i]); at[i] = fmaf(wt4.w, xv[3], at[i]);
      ap[i] = fmaf(wp4.x, xv[0], ap[i]); ap[i] = fmaf(wp4.y, xv[1], ap[i]);
      ap[i] = fmaf(wp4.z, xv[2], ap[i]); ap[i] = fmaf(wp4.w, xv[3], ap[i]);
      ag[i] = fmaf(wg4.x, xv[0], ag[i]); ag[i] = fmaf(wg4.y, xv[1], ag[i]);
      ag[i] = fmaf(wg4.z, xv[2], ag[i]); ag[i] = fmaf(wg4.w, xv[3], ag[i]);
    }
  }

  uint2 wt2, wp2;
  wt2.x = (uint32_t)f2bf(at[0] * LOG2E) | ((uint32_t)f2bf(at[1] * LOG2E) << 16);
  wt2.y = (uint32_t)f2bf(at[2] * LOG2E) | ((uint32_t)f2bf(at[3] * LOG2E) << 16);
  wp2.x = (uint32_t)f2bf(ap[0]) | ((uint32_t)f2bf(ap[1]) << 16);
  wp2.y = (uint32_t)f2bf(ap[2]) | ((uint32_t)f2bf(ap[3]) << 16);
  *(uint2*)(theta_t + ((size_t)(b * N_) + n) * CI + dg * 4) = wt2;
  *(uint2*)(phi_t   + ((size_t)(b * N_) + n) * CI + dg * 4) = wp2;
  #pragma unroll
  for (int i = 0; i < 4; ++i)
    gmat[((size_t)(b * CI) + dg * 4 + i) * N_ + n] = f2bf(ag[i]);
}

// -------- Kernel 2: flash attention (r14 minus per-s sched_barrier) --------
// Write->drain->read order is pinned by the volatile asm "memory" clobber;
// PV MFMAs are data-dependent on the ds_reads. Removing sched_barrier lets
// the scheduler float next-s QK/exp2/cvt into the drain shadow.
__global__ __launch_bounds__(512, 2) void attn_kernel(
    const ushort* __restrict__ theta_t,
    const ushort* __restrict__ phi_t,
    const ushort* __restrict__ gmat,
    const float* __restrict__ Ww, const float* __restrict__ bw,
    const float* __restrict__ x, float* __restrict__ out)
{
  __shared__ union {
    ushort pt[8][2][16 * 64];     // per-wave ping-pong P tiles (main loop)
    float  accS[4][32][64];       // merge acc slots (merge phase)
    float  yl[32 * 66];           // y tile (after final merge sync)
  } Sh;
  __shared__ float mlS[4][8][64]; // merge m/l slots
  __shared__ float WwL[C_ * CI];

  const int tid = threadIdx.x;
  const int lane = tid & 63;
  const int mh = tid >> 6;        // wave = m-eighth 0..7
  const int bid = blockIdx.x;
  const int b = bid & 7;          // batch -> XCD slot (K/V L2-resident)
  const int n0 = (bid >> 3) * 64;
  const int g4 = lane >> 4;
  const int c16 = lane & 15;
  const int sw = (c16 & 7) << 4;

  #pragma unroll
  for (int i = 0; i < 4; ++i) WwL[tid + i * 512] = Ww[tid + i * 512];

  bf16x8 qfrag[4];
  #pragma unroll
  for (int s = 0; s < 4; ++s)
    qfrag[s] = *(const bf16x8*)(theta_t +
        ((size_t)(b * N_ + n0 + s * 16 + c16)) * CI + g4 * 8);

  f32x4 acc[4][2];
  f32x4 cinit[4];                 // = splat(-m_run[s]); lives in regs
  #pragma unroll
  for (int s = 0; s < 4; ++s) {
    acc[s][0] = (f32x4){0.f, 0.f, 0.f, 0.f};
    acc[s][1] = (f32x4){0.f, 0.f, 0.f, 0.f};
    cinit[s]  = (f32x4){0.f, 0.f, 0.f, 0.f};
  }
  float l_lane[4] = {0.f, 0.f, 0.f, 0.f};

  const int mq0 = mh * 512;
  const ushort* kbase = phi_t + ((size_t)(b * N_ + mq0 + c16)) * CI + g4 * 8;
  const ushort* vb0 = gmat + ((size_t)(b * CI + c16)) * N_ + mq0 + g4 * 8;
  const ushort* vb1 = vb0 + (size_t)16 * N_;

  char* pw[2][4]; const char* prd[2][2];
  #pragma unroll
  for (int pb = 0; pb < 2; ++pb) {
    #pragma unroll
    for (int mt = 0; mt < 4; ++mt)
      pw[pb][mt] = (char*)Sh.pt[mh][pb] + ((c16 * 128 + mt * 32 + g4 * 8) ^ sw);
    #pragma unroll
    for (int ks = 0; ks < 2; ++ks)
      prd[pb][ks] = (const char*)Sh.pt[mh][pb] +
                    ((c16 * 128 + ks * 64 + g4 * 16) ^ sw);
  }

  bf16x8 kf[4], kfn[4], vf0[2], vf1[2];
  #pragma unroll
  for (int mt = 0; mt < 4; ++mt)
    kfn[mt] = *(const bf16x8*)(kbase + (size_t)(mt * 16) * CI);

  const int NT = 8;               // 512 rows / 64 per tile
  for (int t = 0; t < NT; ++t) {
    #pragma unroll
    for (int mt = 0; mt < 4; ++mt) kf[mt] = kfn[mt];
    const int tn = (t + 1 < NT) ? t + 1 : t;
    #pragma unroll
    for (int mt = 0; mt < 4; ++mt)
      kfn[mt] = *(const bf16x8*)(kbase + (size_t)(tn * 64 + mt * 16) * CI);
    #pragma unroll
    for (int ks = 0; ks < 2; ++ks) {
      vf0[ks] = *(const bf16x8*)(vb0 + t * 64 + ks * 32);
      vf1[ks] = *(const bf16x8*)(vb1 + t * 64 + ks * 32);
    }

    #pragma unroll
    for (int s = 0; s < 4; ++s) {
      const int pb = s & 1;
      f32x4 f[4];
      #pragma unroll
      for (int mt = 0; mt < 4; ++mt)
        f[mt] = __builtin_amdgcn_mfma_f32_16x16x32_bf16(
            kf[mt], qfrag[s], cinit[s], 0, 0, 0);   // f = K.Q - m (free sub)

      // p = exp2(f); l accumulates; no fmax tree (l-threshold guards range)
      float pv[4][4];
      #pragma unroll
      for (int mt = 0; mt < 4; ++mt) {
        #pragma unroll
        for (int rr = 0; rr < 4; ++rr)
          pv[mt][rr] = __builtin_amdgcn_exp2f(f[mt][rr]);
        l_lane[s] += (pv[mt][0] + pv[mt][1]) + (pv[mt][2] + pv[mt][3]);
      }
      #pragma unroll
      for (int mt = 0; mt < 4; ++mt) {
        uint2 wv;
        wv.x = cvt_pk_bf16(pv[mt][0], pv[mt][1]);
        wv.y = cvt_pk_bf16(pv[mt][2], pv[mt][3]);
        *(uint2*)pw[pb][mt] = wv;
      }
      // write->drain->read pinned by volatile asm + memory clobber; no
      // sched_barrier so independent next-s work can fill the drain shadow.
      asm volatile("s_waitcnt lgkmcnt(0)" ::: "memory");

      #pragma unroll
      for (int ks = 0; ks < 2; ++ks) {
        const bf16x8 pfrag = *(const bf16x8*)prd[pb][ks];
        acc[s][0] = __builtin_amdgcn_mfma_f32_16x16x32_bf16(
            vf0[ks], pfrag, acc[s][0], 0, 0, 0);
        acc[s][1] = __builtin_amdgcn_mfma_f32_16x16x32_bf16(
            vf1[ks], pfrag, acc[s][1], 0, 0, 0);
      }

      // l-threshold rescale: rare, exact power of 2; keeps l,p,acc in range.
      if (__any(l_lane[s] > 0x1p40f)) {
        const float sc = 0x1p-64f;
        acc[s][0] *= sc; acc[s][1] *= sc; l_lane[s] *= sc;
        #pragma unroll
        for (int rr = 0; rr < 4; ++rr) cinit[s][rr] -= 64.f;
      }
    }
  }

  // total l per q-column: sum the 4 g4 partials
  float m_run[4];
  #pragma unroll
  for (int s = 0; s < 4; ++s) {
    l_lane[s] += __shfl_xor(l_lane[s], 16);
    l_lane[s] += __shfl_xor(l_lane[s], 32);
    m_run[s] = -cinit[s][0];
  }

  // ---- split-m merge: max-aware flash combine, 3-round tree (r7-proven) ----
  #pragma unroll
  for (int r = 4; r >= 1; r >>= 1) {
    __syncthreads();
    if (mh >= r && mh < 2 * r) {
      float* ad = &Sh.accS[mh - r][0][0] + lane;
      float* md = &mlS[mh - r][0][0] + lane;
      #pragma unroll
      for (int s = 0; s < 4; ++s) {
        #pragma unroll
        for (int rr = 0; rr < 4; ++rr) {
          ad[(s * 8 + rr) * 64]     = acc[s][0][rr];
          ad[(s * 8 + 4 + rr) * 64] = acc[s][1][rr];
        }
        md[s * 64]       = m_run[s];
        md[(4 + s) * 64] = l_lane[s];
      }
    }
    __syncthreads();
    if (mh < r) {
      const float* as_ = &Sh.accS[mh][0][0] + lane;
      const float* ms_ = &mlS[mh][0][0] + lane;
      #pragma unroll
      for (int s = 0; s < 4; ++s) {
        const float mb = ms_[s * 64];
        const float lb = ms_[(4 + s) * 64];
        const float mM = fmaxf(m_run[s], mb);
        const float ea = __builtin_amdgcn_exp2f(m_run[s] - mM);
        const float eb = __builtin_amdgcn_exp2f(mb - mM);
        #pragma unroll
        for (int rr = 0; rr < 4; ++rr) {
          acc[s][0][rr] = acc[s][0][rr] * ea + as_[(s * 8 + rr) * 64] * eb;
          acc[s][1][rr] = acc[s][1][rr] * ea + as_[(s * 8 + 4 + rr) * 64] * eb;
        }
        l_lane[s] = l_lane[s] * ea + lb * eb;
        m_run[s] = mM;
      }
    }
  }
  __syncthreads();                // all merge reads done; Sh reusable as Yl

  float* const Yl = Sh.yl;        // aliases dead pt/accS (barrier-ordered)
  if (mh == 0) {
    #pragma unroll
    for (int s = 0; s < 4; ++s) {
      const float inv = 1.0f / l_lane[s];
      const int q = s * 16 + c16;
      #pragma unroll
      for (int rr = 0; rr < 4; ++rr) {
        Yl[(g4 * 4 + rr) * 66 + q]      = acc[s][0][rr] * inv;
        Yl[(16 + g4 * 4 + rr) * 66 + q] = acc[s][1][rr] * inv;
      }
    }
  }
  __syncthreads();

  // ---- fused out-projection + residual: out = Ww @ y + bw + x ----
  const int nl = tid & 63;
  const int cg = tid >> 6;
  float oacc[8];
  #pragma unroll
  for (int i = 0; i < 8; ++i) oacc[i] = bw[cg * 8 + i];
  #pragma unroll
  for (int d = 0; d < CI; ++d) {
    const float yv = Yl[d * 66 + nl];
    #pragma unroll
    for (int i = 0; i < 8; ++i)
      oacc[i] = fmaf(WwL[(cg * 8 + i) * CI + d], yv, oacc[i]);
  }
  #pragma unroll
  for (int i = 0; i < 8; ++i) {
    const size_t idx = ((size_t)(b * C_ + cg * 8 + i)) * N_ + n0 + nl;
    out[idx] = oacc[i] + x[idx];
  }
}

extern "C" void kernel_launch(void* const* d_in, const int* in_sizes, int n_in,
                              void* d_out, int out_size, void* d_ws, size_t ws_size,
                              hipStream_t stream) {
  const float* x  = (const float*)d_in[0];
  const float* Wg = (const float*)d_in[1];
  const float* bg = (const float*)d_in[2];
  const float* Wt = (const float*)d_in[3];
  const float* bt = (const float*)d_in[4];
  const float* Wp = (const float*)d_in[5];
  const float* bp = (const float*)d_in[6];
  const float* Ww = (const float*)d_in[7];
  const float* bw = (const float*)d_in[8];
  float* out = (float*)d_out;

  char* ws = (char*)d_ws;
  ushort* theta_t = (ushort*)(ws);
  ushort* phi_t   = (ushort*)(ws + (size_t)2 * 1024 * 1024);
  ushort* gmat    = (ushort*)(ws + (size_t)4 * 1024 * 1024);

  proj_kernel<<<dim3(N_ / 64, B_), 512, 0, stream>>>(
      x, Wg, bg, Wt, bt, Wp, bp, theta_t, phi_t, gmat);
  attn_kernel<<<dim3((N_ / 64) * B_), 512, 0, stream>>>(
      theta_t, phi_t, gmat, Ww, bw, x, out);
}